// Round 15
// baseline (138.426 us; speedup 1.0000x reference)
//
#include <hip/hip_runtime.h>
#include <math.h>

typedef _Float16 h4_t __attribute__((ext_vector_type(4)));
typedef _Float16 h8_t __attribute__((ext_vector_type(8)));
typedef float    f4_t __attribute__((ext_vector_type(4)));

#define NB 128
#define NC 256
#define NQ 64
#define NN 4096
#define TN 64                 // per-tile n-width
#define PPB 8                 // tile-PAIRS per block (each pair = 128 n)
#define NGRP (NN / (2 * TN) / PPB)   // 4 groups per batch -> 512 blocks

// raw workgroup barrier: LDS visibility only — staged global loads stay in
// flight (no vmcnt(0) drain like __syncthreads).
#define BAR_LGKM() do {                                              \
    asm volatile("s_waitcnt lgkmcnt(0)" ::: "memory");               \
    __builtin_amdgcn_s_barrier();                                    \
    asm volatile("" ::: "memory");                                   \
} while (0)

__device__ __forceinline__ float fast_tanh(float x) {
    float e = __builtin_amdgcn_exp2f(x * 2.885390082f);  // exp(2x)
    return 1.f - 2.f * __builtin_amdgcn_rcpf(e + 1.f);
}

// ---------------- KPRE: x_k proj/tanh/bound + wq pack, one launch ----------
__global__ void kpre(const float* __restrict__ wk, const float* __restrict__ bk,
                     const float* __restrict__ xkey, const float* __restrict__ wq,
                     float* __restrict__ kt, float* __restrict__ Mb,
                     _Float16* __restrict__ wqf)
{
    const int bid = blockIdx.x;
    const int tid = threadIdx.x;
    if (bid < 32) {
        const int b = bid * 4 + (tid >> 6);   // one batch per wave
        const int o = tid & 63;
        float a = bk[o];
        #pragma unroll 8
        for (int c = 0; c < NC; ++c)
            a += wk[o * NC + c] * xkey[b * NC + c];
        float t = tanhf(a);
        kt[b * NQ + o] = t;
        float m = fabsf(t);
        #pragma unroll
        for (int mm = 1; mm < 64; mm <<= 1) m += __shfl_xor(m, mm);
        if (o == 0) Mb[b] = m;
    } else {
        const int i = (bid - 32) * 256 + tid;   // 16384
        const int j = i & 3;
        const int l = (i >> 2) & 63;
        const int f = i >> 8;
        const int ks = f >> 2, t = f & 3;
        const int o = t * 16 + (l & 15);
        const int c = ks * 16 + (l >> 4) * 4 + j;
        wqf[i] = (_Float16)wq[o * NC + c];
    }
}

// ---------------- K1: fused main pass over x (read x once) ----------------
// PAIRED-TILE staging: 512 threads stage two adjacent 64-n tiles per step,
// issuing each row's tile-A and tile-B loads back-to-back (256B apart) so the
// memory controller sees 512B-adjacent pairs. 8 waves/CU (1 block), NT loads.
// Waves 0-3 compute tile A (16 rows each), waves 4-7 tile B — round-5 flow.
template<int ATOMIC>
__global__ __launch_bounds__(512, 2) void k_main(
    const float* __restrict__ x, const _Float16* __restrict__ wqf,
    const float* __restrict__ bq, const float* __restrict__ kt,
    const float* __restrict__ Mb, float* __restrict__ w_out,
    float* __restrict__ spart, float* __restrict__ zpart,
    float* __restrict__ sraw, float* __restrict__ Zg)
{
    __shared__ _Float16 xl[2][64 * 256];   // 64 KB (two tiles)
    __shared__ _Float16 wqf_l[16384];      // 32 KB
    __shared__ float wsl[8][16];
    __shared__ float sacc[8][256];         // 8 KB
    __shared__ float zsl[8];

    const int bid  = blockIdx.x;       // NB*NGRP = 512
    const int b    = bid >> 2;
    const int grp  = bid & 3;
    const int tid  = threadIdx.x;      // 0..511
    const int n    = tid & 63;
    const int cg   = tid >> 6;         // 0..7: rows cg*32..+31

    const int w    = tid >> 6;         // wave 0..7
    const int lane = tid & 63;
    const int g    = lane >> 4;
    const int li   = lane & 15;
    const int T    = w >> 2;           // tile 0 (A) / 1 (B)
    const int s    = w & 3;            // row-set within tile

    const float* srcbase = x + ((size_t)b * NC + cg * 32) * NN + n;

    // ---- wq fragments -> LDS (32 KB, reused by all pairs)
    #pragma unroll
    for (int i = 0; i < 4; ++i)
        ((h8_t*)wqf_l)[i * 512 + tid] = ((const h8_t*)wqf)[i * 512 + tid];

    float ktv[4], bqv[4];
    #pragma unroll
    for (int q = 0; q < 4; ++q) {
        ktv[q] = kt[b * NQ + q * 16 + li];
        bqv[q] = bq[q * 16 + li];
    }
    const float Mbb = Mb[b];

    int n0 = grp * (PPB * 2 * TN);   // pair base (1024-n groups)

    // paired loads: row i of this thread's 32 rows; A chunk then B chunk
    // (addresses 256B apart -> MC-adjacent).
    #define LOADP(dA, dB, off)                                                 \
        { _Pragma("unroll")                                                    \
          for (int i = 0; i < 32; ++i) {                                       \
              const float* _r = srcbase + (size_t)i * NN + (off);              \
              dA[i] = __builtin_nontemporal_load(_r);                          \
              dB[i] = __builtin_nontemporal_load(_r + TN);                     \
          } }
    // write one tile's 32 rows at column n (4 x h8 along c)
    #define WRITEP(srcv, buf)                                                  \
        { _Pragma("unroll")                                                    \
          for (int k8 = 0; k8 < 4; ++k8) {                                     \
              h8_t h;                                                          \
              _Pragma("unroll")                                                \
              for (int j = 0; j < 8; ++j) h[j] = (_Float16)srcv[k8 * 8 + j];   \
              const int c   = cg * 32 + k8 * 8;                                \
              const int idx = (n * 256 + c) ^ ((n & 7) << 3);                  \
              *(h8_t*)&xl[buf][idx] = h;                                       \
          } }

    // ---- prologue: stage pair 0
    {
        float pA[32], pB[32];
        LOADP(pA, pB, n0);
        WRITEP(pA, 0); WRITEP(pB, 1);
    }
    BAR_LGKM();   // xl + wqf_l ready

    f4_t a2 = f4_t{0.f, 0.f, 0.f, 0.f};   // partial s[c=4*lane..+3], own rows
    float zacc = 0.f;                      // z partial (li==0 lanes only)

    for (int p = 0; p < PPB; ++p) {
        const bool pf = (p + 1 < PPB);
        float cA[32], cB[32];
        if (pf) LOADP(cA, cB, n0 + 2 * TN);

        const int tn0 = n0 + T * TN;   // this wave's tile base

        // ---- MFMA: x_q[n, o] for own 16 rows of own tile (LDS only)
        f4_t acc[4];
        #pragma unroll
        for (int q = 0; q < 4; ++q) acc[q] = f4_t{0.f, 0.f, 0.f, 0.f};
        #pragma unroll
        for (int ks = 0; ks < 16; ++ks) {
            const int nn   = s * 16 + li;
            const int cA2  = ks * 16 + g * 4;
            const int idxA = (nn * 256 + cA2) ^ ((nn & 7) << 3);
            h4_t a = *(const h4_t*)&xl[T][idxA];
            #pragma unroll
            for (int q = 0; q < 4; ++q) {
                h4_t bf = *(const h4_t*)&wqf_l[((ks * 4 + q) * 64 + lane) * 4];
                acc[q] = __builtin_amdgcn_mfma_f32_16x16x16f16(a, bf, acc[q], 0, 0, 0);
            }
        }

        // ---- energy: e[row 4g+r of own wave] (all 16 li share result)
        float ep[4] = {0.f, 0.f, 0.f, 0.f};
        #pragma unroll
        for (int q = 0; q < 4; ++q) {
            #pragma unroll
            for (int r = 0; r < 4; ++r)
                ep[r] += fast_tanh(acc[q][r] + bqv[q]) * ktv[q];
        }
        #pragma unroll
        for (int r = 0; r < 4; ++r) {
            #pragma unroll
            for (int m = 1; m < 16; m <<= 1)
                ep[r] += __shfl_xor(ep[r], m);
        }

        // ---- w = exp(e - M), wave-local; share within wave via wsl slot
        {
            f4_t wv;
            #pragma unroll
            for (int r = 0; r < 4; ++r)
                wv[r] = __builtin_amdgcn_exp2f((ep[r] - Mbb) * 1.44269504f);
            if (li == 0) {
                *(f4_t*)&w_out[b * NN + tn0 + s * 16 + g * 4] = wv;
                *(f4_t*)&wsl[w][g * 4] = wv;
                zacc += wv[0] + wv[1] + wv[2] + wv[3];
            }
        }
        // read back all 16 row-weights (same wave; compiler orders via lgkmcnt)
        f4_t wrow[4];
        #pragma unroll
        for (int jj = 0; jj < 4; ++jj)
            wrow[jj] = *(const f4_t*)&wsl[w][jj * 4];

        // ---- pass2: s[c] += sum over own 16 rows of x[c,n]*w[n]
        #pragma unroll
        for (int j = 0; j < 16; ++j) {
            const int nn  = s * 16 + j;
            const int idx = (nn * 256 + 4 * lane) ^ ((nn & 7) << 3);
            h4_t xv = *(const h4_t*)&xl[T][idx];
            const float wj = wrow[j >> 2][j & 3];
            a2[0] += (float)xv[0] * wj;
            a2[1] += (float)xv[1] * wj;
            a2[2] += (float)xv[2] * wj;
            a2[3] += (float)xv[3] * wj;
        }

        BAR_LGKM();   // all xl reads retired; staged loads still in flight
        if (pf) { WRITEP(cA, 0); WRITEP(cB, 1); }
        n0 += 2 * TN;
        BAR_LGKM();   // xl holds pair p+1
    }
    #undef LOADP
    #undef WRITEP

    // ---- cross-wave reduction of s and z
    {
        float z = zacc;
        z += __shfl_xor(z, 16);
        z += __shfl_xor(z, 32);
        if (lane == 0) zsl[w] = z;
    }
    *(f4_t*)&sacc[w][4 * lane] = a2;
    __syncthreads();

    if (tid < NC) {
        float ssum = 0.f;
        #pragma unroll
        for (int ww = 0; ww < 8; ++ww) ssum += sacc[ww][tid];
        if (ATOMIC) {
            atomicAdd(&sraw[b * NC + tid], ssum);
            if (tid == 0) {
                float zt = 0.f;
                #pragma unroll
                for (int ww = 0; ww < 8; ++ww) zt += zsl[ww];
                atomicAdd(&Zg[b], zt);
            }
        } else {
            spart[((size_t)(b * NGRP + grp)) * NC + tid] = ssum;
            if (tid == 0) {
                float zt = 0.f;
                #pragma unroll
                for (int ww = 0; ww < 8; ++ww) zt += zsl[ww];
                zpart[b * NGRP + grp] = zt;
            }
        }
    }
}

// ---------------- K2: per-batch reduce + x_r + t_pre (native wv/wt layout) ----
__global__ void k2(const float* __restrict__ spart, const float* __restrict__ zpart,
                   const float* __restrict__ sraw,  const float* __restrict__ Zg,
                   const float* __restrict__ wv,    const float* __restrict__ wt,
                   const float* __restrict__ bv,    const float* __restrict__ bt,
                   const float* __restrict__ xkey,  float* __restrict__ tpre,
                   float* __restrict__ Zout, int atomicMode)
{
    const int b = blockIdx.x;
    const int tid = threadIdx.x;
    __shared__ float s_l[NC];
    __shared__ float d_l[NC];
    __shared__ float zsh;

    float ssum;
    if (atomicMode) {
        ssum = sraw[b * NC + tid];
        if (tid == 0) { zsh = Zg[b]; Zout[b] = zsh; }
    } else {
        ssum = 0.f;
        #pragma unroll
        for (int T = 0; T < NGRP; ++T)
            ssum += spart[((size_t)(b * NGRP + T)) * NC + tid];
        if (tid == 0) {
            float z = 0.f;
            #pragma unroll
            for (int T = 0; T < NGRP; ++T) z += zpart[b * NGRP + T];
            zsh = z; Zout[b] = z;
        }
    }
    s_l[tid] = ssum;
    __syncthreads();

    const float invZ = 1.0f / zsh;
    {
        const f4_t* wrow = (const f4_t*)&wv[(size_t)tid * NC];
        float a = 0.f;
        #pragma unroll 8
        for (int k = 0; k < NC / 4; ++k) {
            const f4_t w4 = wrow[k];
            const f4_t s4 = *(const f4_t*)&s_l[k * 4];
            a += w4[0] * s4[0] + w4[1] * s4[1] + w4[2] * s4[2] + w4[3] * s4[3];
        }
        d_l[tid] = xkey[b * NC + tid] - (bv[tid] + a * invZ);
    }
    __syncthreads();
    {
        const f4_t* wrow = (const f4_t*)&wt[(size_t)tid * NC];
        float t = bt[tid];
        #pragma unroll 8
        for (int k = 0; k < NC / 4; ++k) {
            const f4_t w4 = wrow[k];
            const f4_t d4 = *(const f4_t*)&d_l[k * 4];
            t += w4[0] * d4[0] + w4[1] * d4[1] + w4[2] * d4[2] + w4[3] * d4[3];
        }
        tpre[b * NC + tid] = t;
    }
}

// ---------------- KPOST: attention normalize (blocks 0..2047) + BN (2048..2055) ----
__global__ void kpost(const float* __restrict__ w, const float* __restrict__ Z,
                      const float* __restrict__ tpre, const float* __restrict__ xkey,
                      const float* __restrict__ gma, const float* __restrict__ bta,
                      float* __restrict__ attn_out, float* __restrict__ out)
{
    const int bid = blockIdx.x;
    if (bid < 2048) {
        const int i = bid * 256 + threadIdx.x;   // 524288
        const int b = i >> 12;
        attn_out[i] = w[i] / Z[b];
        return;
    }
    __shared__ float sA[8][32], sB[8][32];
    __shared__ float mean_s[32], rs_s[32];
    const int cl = threadIdx.x & 31;
    const int bg = threadIdx.x >> 5;       // 8 groups of 16 b
    const int c  = (bid - 2048) * 32 + cl;

    float v[16];
    float s = 0.f, s2 = 0.f;
    #pragma unroll
    for (int i = 0; i < 16; ++i) {
        v[i] = tpre[(bg * 16 + i) * NC + c];
        s += v[i]; s2 += v[i] * v[i];
    }
    sA[bg][cl] = s; sB[bg][cl] = s2;
    __syncthreads();
    if (bg == 0) {
        float S = 0.f, S2 = 0.f;
        #pragma unroll
        for (int g2 = 0; g2 < 8; ++g2) { S += sA[g2][cl]; S2 += sB[g2][cl]; }
        const float mean = S * (1.f / NB);
        const float var  = S2 * (1.f / NB) - mean * mean;
        mean_s[cl] = mean;
        rs_s[cl]   = rsqrtf(var + 1e-5f);
    }
    __syncthreads();
    const float mean = mean_s[cl], rs = rs_s[cl];
    const float gc = gma[c], bc = bta[c];
    #pragma unroll
    for (int i = 0; i < 16; ++i) {
        float t2 = (v[i] - mean) * rs * gc + bc;
        t2 = t2 > 0.f ? t2 : 0.f;
        out[(bg * 16 + i) * NC + c] = xkey[(bg * 16 + i) * NC + c] + t2;
    }
}

extern "C" void kernel_launch(void* const* d_in, const int* in_sizes, int n_in,
                              void* d_out, int out_size, void* d_ws, size_t ws_size,
                              hipStream_t stream)
{
    const float* x    = (const float*)d_in[0];
    const float* xkey = (const float*)d_in[1];
    const float* wq   = (const float*)d_in[2];
    const float* bq   = (const float*)d_in[3];
    const float* wk   = (const float*)d_in[4];
    const float* bk   = (const float*)d_in[5];
    const float* wvm  = (const float*)d_in[6];
    const float* bv   = (const float*)d_in[7];
    const float* wtm  = (const float*)d_in[8];
    const float* bt   = (const float*)d_in[9];
    const float* gma  = (const float*)d_in[10];
    const float* bta  = (const float*)d_in[11];
    float* out = (float*)d_out;

    char* ws = (char*)d_ws;
    size_t off = 0;
    auto take = [&](size_t bytes) -> char* {
        char* p = ws + off;
        off = (off + bytes + 255) & ~(size_t)255;
        return p;
    };
    _Float16* wqf = (_Float16*)take(16384 * 2);
    float* kt   = (float*)take(NB * NQ * 4);
    float* Mb   = (float*)take(NB * 4);
    float* wbuf = (float*)take((size_t)NB * NN * 4);
    float* tpre = (float*)take(NB * NC * 4);
    float* Zf   = (float*)take(NB * 4);

    const size_t base = off;
    float* spart = (float*)take((size_t)NB * NGRP * NC * 4);
    float* zpart = (float*)take(NB * NGRP * 4);
    const bool det = (off <= ws_size);
    float* sraw = nullptr;
    float* Zg   = nullptr;
    if (!det) {
        off = base;
        sraw = (float*)take(NB * NC * 4);
        Zg   = (float*)take(NB * 4);
        hipMemsetAsync(sraw, 0, NB * NC * 4, stream);
        hipMemsetAsync(Zg, 0, NB * 4, stream);
    }

    kpre<<<96, 256, 0, stream>>>(wk, bk, xkey, wq, kt, Mb, wqf);
    if (det)
        k_main<0><<<NB * NGRP, 512, 0, stream>>>(x, wqf, bq, kt, Mb, wbuf,
                                                 spart, zpart, nullptr, nullptr);
    else
        k_main<1><<<NB * NGRP, 512, 0, stream>>>(x, wqf, bq, kt, Mb, wbuf,
                                                 nullptr, nullptr, sraw, Zg);
    k2<<<NB, 256, 0, stream>>>(spart, zpart, sraw, Zg, wvm, wtm, bv, bt, xkey,
                               tpre, Zf, det ? 0 : 1);
    kpost<<<2056, 256, 0, stream>>>(wbuf, Zf, tpre, xkey, gma, bta,
                                    out + NB * NC, out);
}

// Round 16
// 125.869 us; speedup vs baseline: 1.0998x; 1.0998x over previous
//
#include <hip/hip_runtime.h>
#include <math.h>

typedef _Float16 h4_t __attribute__((ext_vector_type(4)));
typedef _Float16 h8_t __attribute__((ext_vector_type(8)));
typedef float    f4_t __attribute__((ext_vector_type(4)));

#define NB 128
#define NC 256
#define NQ 64
#define NN 4096
#define TN 64
#define TPB 8                 // tiles per block
#define NGRP (NN / TN / TPB)  // 8 tile-groups per batch

// raw workgroup barrier: LDS visibility only — staged global loads stay in
// flight (no vmcnt(0) drain like __syncthreads).
#define BAR_LGKM() do {                                              \
    asm volatile("s_waitcnt lgkmcnt(0)" ::: "memory");               \
    __builtin_amdgcn_s_barrier();                                    \
    asm volatile("" ::: "memory");                                   \
} while (0)

__device__ __forceinline__ float fast_tanh(float x) {
    float e = __builtin_amdgcn_exp2f(x * 2.885390082f);  // exp(2x)
    return 1.f - 2.f * __builtin_amdgcn_rcpf(e + 1.f);
}

// ---------------- KPRE: k0a (x_k proj/tanh/bound) + k0b (wq pack), one launch ----
// blocks 0..31: 4 batches each (one per wave). blocks 32..95: wq fragment pack.
__global__ void kpre(const float* __restrict__ wk, const float* __restrict__ bk,
                     const float* __restrict__ xkey, const float* __restrict__ wq,
                     float* __restrict__ kt, float* __restrict__ Mb,
                     _Float16* __restrict__ wqf)
{
    const int bid = blockIdx.x;
    const int tid = threadIdx.x;
    if (bid < 32) {
        const int b = bid * 4 + (tid >> 6);   // one batch per wave
        const int o = tid & 63;
        float a = bk[o];
        #pragma unroll 8
        for (int c = 0; c < NC; ++c)
            a += wk[o * NC + c] * xkey[b * NC + c];
        float t = tanhf(a);
        kt[b * NQ + o] = t;
        float m = fabsf(t);
        #pragma unroll
        for (int mm = 1; mm < 64; mm <<= 1) m += __shfl_xor(m, mm);
        if (o == 0) Mb[b] = m;
    } else {
        const int i = (bid - 32) * 256 + tid;   // 16384
        const int j = i & 3;
        const int l = (i >> 2) & 63;
        const int f = i >> 8;
        const int ks = f >> 2, t = f & 3;
        const int o = t * 16 + (l & 15);
        const int c = ks * 16 + (l >> 4) * 4 + j;
        wqf[i] = (_Float16)wq[o * NC + c];
    }
}

// ---------------- K1: fused main pass over x (read x once) ----------------
// Round-5 winner + non-temporal x loads (zero-reuse stream; skip L2 alloc).
template<int ATOMIC>
__global__ __launch_bounds__(256, 2) void k_main(
    const float* __restrict__ x, const _Float16* __restrict__ wqf,
    const float* __restrict__ bq, const float* __restrict__ kt,
    const float* __restrict__ Mb, float* __restrict__ w_out,
    float* __restrict__ spart, float* __restrict__ zpart,
    float* __restrict__ sraw, float* __restrict__ Zg)
{
    __shared__ _Float16 xl[64 * 256];
    __shared__ _Float16 wqf_l[16384];
    __shared__ float wsl[4][16];
    __shared__ float sacc[4][256];
    __shared__ float zsl[4];

    const int bid  = blockIdx.x;       // NB*NGRP = 1024
    const int b    = bid >> 3;
    const int grp  = bid & 7;
    const int tid  = threadIdx.x;
    const int n    = tid & 63;
    const int cg   = tid >> 6;

    const int wid  = tid >> 6;
    const int lane = tid & 63;
    const int g    = lane >> 4;
    const int li   = lane & 15;

    const float* srcbase = x + ((size_t)b * NC + cg * 64) * NN + n;

    // ---- wq fragments -> LDS (32 KB, reused by all TPB tiles)
    #pragma unroll
    for (int i = 0; i < 8; ++i)
        ((h8_t*)wqf_l)[i * 256 + tid] = ((const h8_t*)wqf)[i * 256 + tid];

    float ktv[4], bqv[4];
    #pragma unroll
    for (int q = 0; q < 4; ++q) {
        ktv[q] = kt[b * NQ + q * 16 + li];
        bqv[q] = bq[q * 16 + li];
    }
    const float Mbb = Mb[b];

    int n0 = grp * (TPB * TN);

    #define LOADC(dst, ch, off)                                                \
        { const float* _s = srcbase + (off);                                   \
          _Pragma("unroll")                                                    \
          for (int i = 0; i < 16; ++i)                                         \
              dst[i] = __builtin_nontemporal_load(&_s[(size_t)((ch)*16 + i) * NN]); }
    #define WRITEC(srcv, ch)                                                   \
        { _Pragma("unroll")                                                    \
          for (int k8 = 0; k8 < 2; ++k8) {                                     \
              h8_t h;                                                          \
              _Pragma("unroll")                                                \
              for (int j = 0; j < 8; ++j) h[j] = (_Float16)srcv[k8 * 8 + j];   \
              const int c   = cg * 64 + (ch) * 16 + k8 * 8;                    \
              const int idx = (n * 256 + c) ^ ((n & 7) << 3);                  \
              *(h8_t*)&xl[idx] = h;                                            \
          } }

    // ---- prologue: stage tile 0
    {
        float p0[16], p1[16], p2[16], p3[16];
        LOADC(p0, 0, n0); LOADC(p1, 1, n0); LOADC(p2, 2, n0); LOADC(p3, 3, n0);
        WRITEC(p0, 0); WRITEC(p1, 1); WRITEC(p2, 2); WRITEC(p3, 3);
    }
    BAR_LGKM();   // xl + wqf_l ready

    f4_t a2 = f4_t{0.f, 0.f, 0.f, 0.f};   // partial s[c=4*lane..+3], own rows
    float zacc = 0.f;                      // z partial (li==0 lanes only)

    for (int t = 0; t < TPB; ++t) {
        const bool pf = (t + 1 < TPB);
        float c0[16], c1[16], c2[16], c3[16];
        if (pf) LOADC(c0, 0, n0 + TN);

        // ---- MFMA: x_q[n, o] for own 16 rows (LDS only)
        f4_t acc[4];
        #pragma unroll
        for (int q = 0; q < 4; ++q) acc[q] = f4_t{0.f, 0.f, 0.f, 0.f};
        #pragma unroll
        for (int ks = 0; ks < 8; ++ks) {
            const int nn   = wid * 16 + li;
            const int cA   = ks * 16 + g * 4;
            const int idxA = (nn * 256 + cA) ^ ((nn & 7) << 3);
            h4_t a = *(const h4_t*)&xl[idxA];
            #pragma unroll
            for (int q = 0; q < 4; ++q) {
                h4_t bf = *(const h4_t*)&wqf_l[((ks * 4 + q) * 64 + lane) * 4];
                acc[q] = __builtin_amdgcn_mfma_f32_16x16x16f16(a, bf, acc[q], 0, 0, 0);
            }
        }
        if (pf) LOADC(c1, 1, n0 + TN);
        #pragma unroll
        for (int ks = 8; ks < 16; ++ks) {
            const int nn   = wid * 16 + li;
            const int cA   = ks * 16 + g * 4;
            const int idxA = (nn * 256 + cA) ^ ((nn & 7) << 3);
            h4_t a = *(const h4_t*)&xl[idxA];
            #pragma unroll
            for (int q = 0; q < 4; ++q) {
                h4_t bf = *(const h4_t*)&wqf_l[((ks * 4 + q) * 64 + lane) * 4];
                acc[q] = __builtin_amdgcn_mfma_f32_16x16x16f16(a, bf, acc[q], 0, 0, 0);
            }
        }
        if (pf) LOADC(c2, 2, n0 + TN);

        // ---- energy: e[row 4g+r of own wave] (all 16 li share result)
        float ep[4] = {0.f, 0.f, 0.f, 0.f};
        #pragma unroll
        for (int q = 0; q < 4; ++q) {
            #pragma unroll
            for (int r = 0; r < 4; ++r)
                ep[r] += fast_tanh(acc[q][r] + bqv[q]) * ktv[q];
        }
        #pragma unroll
        for (int r = 0; r < 4; ++r) {
            #pragma unroll
            for (int m = 1; m < 16; m <<= 1)
                ep[r] += __shfl_xor(ep[r], m);
        }
        if (pf) LOADC(c3, 3, n0 + TN);

        // ---- w = exp(e - M), wave-local; share within wave via wsl slot
        {
            f4_t wv;
            #pragma unroll
            for (int r = 0; r < 4; ++r)
                wv[r] = __builtin_amdgcn_exp2f((ep[r] - Mbb) * 1.44269504f);
            if (li == 0) {
                *(f4_t*)&w_out[b * NN + n0 + wid * 16 + g * 4] = wv;
                *(f4_t*)&wsl[wid][g * 4] = wv;
                zacc += wv[0] + wv[1] + wv[2] + wv[3];
            }
        }
        // read back all 16 row-weights (same wave; compiler orders via lgkmcnt)
        f4_t wrow[4];
        #pragma unroll
        for (int jj = 0; jj < 4; ++jj)
            wrow[jj] = *(const f4_t*)&wsl[wid][jj * 4];

        // ---- pass2: s[c] += sum over own 16 rows of x[c,n]*w[n]
        #pragma unroll
        for (int j = 0; j < 16; ++j) {
            const int nn  = wid * 16 + j;
            const int idx = (nn * 256 + 4 * lane) ^ ((nn & 7) << 3);
            h4_t xv = *(const h4_t*)&xl[idx];
            const float wj = wrow[j >> 2][j & 3];
            a2[0] += (float)xv[0] * wj;
            a2[1] += (float)xv[1] * wj;
            a2[2] += (float)xv[2] * wj;
            a2[3] += (float)xv[3] * wj;
        }

        BAR_LGKM();   // all xl reads retired; staged loads still in flight
        if (pf) { WRITEC(c0, 0); WRITEC(c1, 1); WRITEC(c2, 2); WRITEC(c3, 3); }
        n0 += TN;
        BAR_LGKM();   // xl holds tile t+1
    }
    #undef LOADC
    #undef WRITEC

    // ---- cross-wave reduction of s and z
    {
        float z = zacc;
        z += __shfl_xor(z, 16);
        z += __shfl_xor(z, 32);
        if (lane == 0) zsl[wid] = z;
    }
    *(f4_t*)&sacc[wid][4 * lane] = a2;
    __syncthreads();

    const float ssum = sacc[0][tid] + sacc[1][tid] + sacc[2][tid] + sacc[3][tid];
    if (ATOMIC) {
        atomicAdd(&sraw[b * NC + tid], ssum);
        if (tid == 0) atomicAdd(&Zg[b], zsl[0] + zsl[1] + zsl[2] + zsl[3]);
    } else {
        spart[((size_t)(b * NGRP + grp)) * NC + tid] = ssum;
        if (tid == 0) zpart[b * NGRP + grp] = zsl[0] + zsl[1] + zsl[2] + zsl[3];
    }
}

// ---------------- K2: per-batch reduce + x_r + t_pre (native wv/wt layout) ----
__global__ void k2(const float* __restrict__ spart, const float* __restrict__ zpart,
                   const float* __restrict__ sraw,  const float* __restrict__ Zg,
                   const float* __restrict__ wv,    const float* __restrict__ wt,
                   const float* __restrict__ bv,    const float* __restrict__ bt,
                   const float* __restrict__ xkey,  float* __restrict__ tpre,
                   float* __restrict__ Zout, int atomicMode)
{
    const int b = blockIdx.x;
    const int tid = threadIdx.x;
    __shared__ float s_l[NC];
    __shared__ float d_l[NC];
    __shared__ float zsh;

    float ssum;
    if (atomicMode) {
        ssum = sraw[b * NC + tid];
        if (tid == 0) { zsh = Zg[b]; Zout[b] = zsh; }
    } else {
        ssum = 0.f;
        #pragma unroll
        for (int T = 0; T < NGRP; ++T)
            ssum += spart[((size_t)(b * NGRP + T)) * NC + tid];
        if (tid < NGRP) {
            float z = zpart[b * NGRP + tid];
            #pragma unroll
            for (int m = 1; m < NGRP; m <<= 1) z += __shfl_xor(z, m);
            if (tid == 0) { zsh = z; Zout[b] = z; }
        }
    }
    s_l[tid] = ssum;
    __syncthreads();

    const float invZ = 1.0f / zsh;
    {
        const f4_t* wrow = (const f4_t*)&wv[(size_t)tid * NC];
        float a = 0.f;
        #pragma unroll 8
        for (int k = 0; k < NC / 4; ++k) {
            const f4_t w4 = wrow[k];
            const f4_t s4 = *(const f4_t*)&s_l[k * 4];
            a += w4[0] * s4[0] + w4[1] * s4[1] + w4[2] * s4[2] + w4[3] * s4[3];
        }
        d_l[tid] = xkey[b * NC + tid] - (bv[tid] + a * invZ);
    }
    __syncthreads();
    {
        const f4_t* wrow = (const f4_t*)&wt[(size_t)tid * NC];
        float t = bt[tid];
        #pragma unroll 8
        for (int k = 0; k < NC / 4; ++k) {
            const f4_t w4 = wrow[k];
            const f4_t d4 = *(const f4_t*)&d_l[k * 4];
            t += w4[0] * d4[0] + w4[1] * d4[1] + w4[2] * d4[2] + w4[3] * d4[3];
        }
        tpre[b * NC + tid] = t;
    }
}

// ---------------- KPOST: k4 (attention = w/Z, blocks 0..2047) + k3 (BN, 2048..2055) ----
__global__ void kpost(const float* __restrict__ w, const float* __restrict__ Z,
                      const float* __restrict__ tpre, const float* __restrict__ xkey,
                      const float* __restrict__ gma, const float* __restrict__ bta,
                      float* __restrict__ attn_out, float* __restrict__ out)
{
    const int bid = blockIdx.x;
    if (bid < 2048) {
        const int i = bid * 256 + threadIdx.x;   // 524288
        const int b = i >> 12;
        attn_out[i] = w[i] / Z[b];
        return;
    }
    // ---- BatchNorm over batch + ReLU + residual
    __shared__ float sA[8][32], sB[8][32];
    __shared__ float mean_s[32], rs_s[32];
    const int cl = threadIdx.x & 31;
    const int bg = threadIdx.x >> 5;       // 8 groups of 16 b
    const int c  = (bid - 2048) * 32 + cl;

    float v[16];
    float s = 0.f, s2 = 0.f;
    #pragma unroll
    for (int i = 0; i < 16; ++i) {
        v[i] = tpre[(bg * 16 + i) * NC + c];
        s += v[i]; s2 += v[i] * v[i];
    }
    sA[bg][cl] = s; sB[bg][cl] = s2;
    __syncthreads();
    if (bg == 0) {
        float S = 0.f, S2 = 0.f;
        #pragma unroll
        for (int g2 = 0; g2 < 8; ++g2) { S += sA[g2][cl]; S2 += sB[g2][cl]; }
        const float mean = S * (1.f / NB);
        const float var  = S2 * (1.f / NB) - mean * mean;
        mean_s[cl] = mean;
        rs_s[cl]   = rsqrtf(var + 1e-5f);
    }
    __syncthreads();
    const float mean = mean_s[cl], rs = rs_s[cl];
    const float gc = gma[c], bc = bta[c];
    #pragma unroll
    for (int i = 0; i < 16; ++i) {
        float t2 = (v[i] - mean) * rs * gc + bc;
        t2 = t2 > 0.f ? t2 : 0.f;
        out[(bg * 16 + i) * NC + c] = xkey[(bg * 16 + i) * NC + c] + t2;
    }
}

extern "C" void kernel_launch(void* const* d_in, const int* in_sizes, int n_in,
                              void* d_out, int out_size, void* d_ws, size_t ws_size,
                              hipStream_t stream)
{
    const float* x    = (const float*)d_in[0];
    const float* xkey = (const float*)d_in[1];
    const float* wq   = (const float*)d_in[2];
    const float* bq   = (const float*)d_in[3];
    const float* wk   = (const float*)d_in[4];
    const float* bk   = (const float*)d_in[5];
    const float* wvm  = (const float*)d_in[6];
    const float* bv   = (const float*)d_in[7];
    const float* wtm  = (const float*)d_in[8];
    const float* bt   = (const float*)d_in[9];
    const float* gma  = (const float*)d_in[10];
    const float* bta  = (const float*)d_in[11];
    float* out = (float*)d_out;

    char* ws = (char*)d_ws;
    size_t off = 0;
    auto take = [&](size_t bytes) -> char* {
        char* p = ws + off;
        off = (off + bytes + 255) & ~(size_t)255;
        return p;
    };
    _Float16* wqf = (_Float16*)take(16384 * 2);
    float* kt   = (float*)take(NB * NQ * 4);
    float* Mb   = (float*)take(NB * 4);
    float* wbuf = (float*)take((size_t)NB * NN * 4);
    float* tpre = (float*)take(NB * NC * 4);
    float* Zf   = (float*)take(NB * 4);

    const size_t base = off;
    float* spart = (float*)take((size_t)NB * NGRP * NC * 4);
    float* zpart = (float*)take(NB * NGRP * 4);
    const bool det = (off <= ws_size);
    float* sraw = nullptr;
    float* Zg   = nullptr;
    if (!det) {
        off = base;
        sraw = (float*)take(NB * NC * 4);
        Zg   = (float*)take(NB * 4);
        hipMemsetAsync(sraw, 0, NB * NC * 4, stream);
        hipMemsetAsync(Zg, 0, NB * 4, stream);
    }

    kpre<<<96, 256, 0, stream>>>(wk, bk, xkey, wq, kt, Mb, wqf);
    if (det)
        k_main<0><<<NB * NGRP, 256, 0, stream>>>(x, wqf, bq, kt, Mb, wbuf,
                                                 spart, zpart, nullptr, nullptr);
    else
        k_main<1><<<NB * NGRP, 256, 0, stream>>>(x, wqf, bq, kt, Mb, wbuf,
                                                 nullptr, nullptr, sraw, Zg);
    k2<<<NB, 256, 0, stream>>>(spart, zpart, sraw, Zg, wvm, wtm, bv, bt, xkey,
                               tpre, Zf, det ? 0 : 1);
    kpost<<<2056, 256, 0, stream>>>(wbuf, Zf, tpre, xkey, gma, bta,
                                    out + NB * NC, out);
}